// Round 1
// baseline (297.277 us; speedup 1.0000x reference)
//
#include <hip/hip_runtime.h>

#define B_TOT 65536
#define T_STEPS 10
#define D_IN 16
#define H 64
#define G4H 256
#define D_MLP 30
#define D_OUT 4
#define BTILE 64
#define STRIDE 152  // 144 used cols (x16|h1:64|h2:64), padded; 304B row = 76 words -> 2-way conflicts only

typedef short short8 __attribute__((ext_vector_type(8)));
typedef short short4_t __attribute__((ext_vector_type(4)));
typedef float float4_t __attribute__((ext_vector_type(4)));
typedef __bf16 bf16x8_t __attribute__((ext_vector_type(8)));

static __device__ __forceinline__ short f2bf(float f) {
    unsigned u = __builtin_bit_cast(unsigned, f);
    unsigned r = (u + 0x7FFFu + ((u >> 16) & 1u)) >> 16;
    return (short)(unsigned short)r;
}
static __device__ __forceinline__ float bf2f(short s) {
    unsigned u = ((unsigned)(unsigned short)s) << 16;
    return __builtin_bit_cast(float, u);
}
static __device__ __forceinline__ float4_t mfma16(short8 a, short8 b, float4_t c) {
    return __builtin_amdgcn_mfma_f32_16x16x32_bf16(
        __builtin_bit_cast(bf16x8_t, a), __builtin_bit_cast(bf16x8_t, b), c, 0, 0, 0);
}
static __device__ __forceinline__ float sigm(float x) {
    return __builtin_amdgcn_rcpf(1.0f + __expf(-x));
}
static __device__ __forceinline__ float tanh_f(float x) {
    return 1.0f - 2.0f * __builtin_amdgcn_rcpf(1.0f + __expf(2.0f * x));
}

// Build WU1 = [W1(16); U1(64); zeros(16)] (96x256 bf16), WU2 = [Wd@W2(64); U2(64)] (128x256 bf16),
// bz1 = b1, bz2 = bd@W2 + b2.
__global__ void precompute_weights(const float* __restrict__ W1, const float* __restrict__ U1,
                                   const float* __restrict__ b1, const float* __restrict__ Wd,
                                   const float* __restrict__ bd, const float* __restrict__ W2,
                                   const float* __restrict__ U2, const float* __restrict__ b2,
                                   short* __restrict__ wu1, short* __restrict__ wu2,
                                   float* __restrict__ bz1, float* __restrict__ bz2) {
    const int j = threadIdx.x;  // 0..255 (one output column)
    for (int r = 0; r < 96; ++r) {
        float v = 0.0f;
        if (r < 16)      v = W1[r * G4H + j];
        else if (r < 80) v = U1[(r - 16) * G4H + j];
        wu1[r * G4H + j] = f2bf(v);
    }
    for (int r = 0; r < 64; ++r) {
        float s = 0.0f;
        for (int k = 0; k < D_MLP; ++k) s += Wd[r * D_MLP + k] * W2[k * G4H + j];
        wu2[r * G4H + j] = f2bf(s);
    }
    for (int r = 0; r < 64; ++r) wu2[(64 + r) * G4H + j] = f2bf(U2[r * G4H + j]);
    bz1[j] = b1[j];
    float s = b2[j];
    for (int k = 0; k < D_MLP; ++k) s += bd[k] * W2[k * G4H + j];
    bz2[j] = s;
}

__global__ __launch_bounds__(256, 2) void lstm_fused(
    const float* __restrict__ x, const short* __restrict__ wu1, const short* __restrict__ wu2,
    const float* __restrict__ bz1, const float* __restrict__ bz2,
    const float* __restrict__ Wf, const float* __restrict__ bfin, float* __restrict__ out) {
    __shared__ __align__(16) short Abuf[BTILE * STRIDE];  // cols: [0,16)=x_t  [16,80)=h1  [80,144)=h2

    const int tid  = threadIdx.x;
    const int lane = tid & 63;
    const int wave = tid >> 6;         // 0..3
    const int q    = lane >> 4;        // k-quad
    const int n    = lane & 15;        // col-in-tile / row-in-A
    const int b0   = blockIdx.x * BTILE;

    // ---- persistent weight B-fragments (registers) ----
    // wave w owns gate-col range [g*64 + w*16, +16) for each gate g (i,f,g,o aligned per-lane)
    short8 wz1[4][3];
    short8 wz2[4][4];
    float bz1v[4], bz2v[4];
#pragma unroll
    for (int g = 0; g < 4; ++g) {
        const int col = g * 64 + wave * 16 + n;
#pragma unroll
        for (int k = 0; k < 3; ++k) {
#pragma unroll
            for (int j = 0; j < 8; ++j)
                wz1[g][k][j] = wu1[(k * 32 + q * 8 + j) * G4H + col];
        }
#pragma unroll
        for (int k = 0; k < 4; ++k) {
#pragma unroll
            for (int j = 0; j < 8; ++j)
                wz2[g][k][j] = wu2[(k * 32 + q * 8 + j) * G4H + col];
        }
        bz1v[g] = bz1[col];
        bz2v[g] = bz2[col];
    }

    // zero LDS (h1/h2 start at 0; x cols overwritten each t)
    for (int i = tid; i < BTILE * STRIDE; i += 256) Abuf[i] = 0;

    float4_t c1[4], c2[4];
#pragma unroll
    for (int m = 0; m < 4; ++m) { c1[m] = (float4_t){0,0,0,0}; c2[m] = (float4_t){0,0,0,0}; }

    const int xr = tid >> 2, xs = tid & 3;  // x staging: row 0..63, 4-float segment 0..3
    const float* xbase = x + (size_t)(b0 + xr) * (T_STEPS * D_IN) + xs * 4;

    __syncthreads();  // zero-init visible before first stage/read

    for (int t = 0; t < T_STEPS; ++t) {
        // ---- stage x_t -> Abuf cols [0,16) as bf16 ----
        {
            const float4 xv = *(const float4*)(xbase + t * D_IN);
            short4_t s4;
            s4[0] = f2bf(xv.x); s4[1] = f2bf(xv.y); s4[2] = f2bf(xv.z); s4[3] = f2bf(xv.w);
            *(short4_t*)&Abuf[xr * STRIDE + xs * 4] = s4;
        }
        __syncthreads();  // (1) x staged; prior h writes visible

        float4_t acc[4][4];
        // ---- z1 = [x | h1_prev | (h2 cols * zero-pad rows)] @ WU1 ----
#pragma unroll
        for (int m = 0; m < 4; ++m) {
            const int arow = (16 * m + n) * STRIDE + q * 8;
            const short8 a0 = *(const short8*)&Abuf[arow + 0];
            const short8 a1 = *(const short8*)&Abuf[arow + 32];
            const short8 a2 = *(const short8*)&Abuf[arow + 64];
#pragma unroll
            for (int g = 0; g < 4; ++g) {
                float4_t c = (float4_t){0,0,0,0};
                c = mfma16(a0, wz1[g][0], c);
                c = mfma16(a1, wz1[g][1], c);
                c = mfma16(a2, wz1[g][2], c);
                acc[m][g] = c;
            }
        }
        __syncthreads();  // (2) all waves done reading old h1

        // ---- LSTM1 gates (tanh), write new h1 ----
#pragma unroll
        for (int m = 0; m < 4; ++m) {
#pragma unroll
            for (int j = 0; j < 4; ++j) {
                const float iv = sigm(acc[m][0][j] + bz1v[0]);
                const float fv = sigm(acc[m][1][j] + bz1v[1]);
                const float gv = tanh_f(acc[m][2][j] + bz1v[2]);
                const float ov = sigm(acc[m][3][j] + bz1v[3]);
                const float cn = fv * c1[m][j] + iv * gv;
                c1[m][j] = cn;
                const float hv = ov * tanh_f(cn);
                // C/D layout: row = 16m + q*4 + j, col(h) = wave*16 + n
                Abuf[(16 * m + q * 4 + j) * STRIDE + 16 + wave * 16 + n] = f2bf(hv);
            }
        }
        __syncthreads();  // (3) new h1 visible

        // ---- z2 = [h1_new | h2_prev] @ [Wc; U2] ----
#pragma unroll
        for (int m = 0; m < 4; ++m) {
            const int arow = (16 * m + n) * STRIDE + q * 8;
            const short8 a0 = *(const short8*)&Abuf[arow + 16];
            const short8 a1 = *(const short8*)&Abuf[arow + 48];
            const short8 a2 = *(const short8*)&Abuf[arow + 80];
            const short8 a3 = *(const short8*)&Abuf[arow + 112];
#pragma unroll
            for (int g = 0; g < 4; ++g) {
                float4_t c = (float4_t){0,0,0,0};
                c = mfma16(a0, wz2[g][0], c);
                c = mfma16(a1, wz2[g][1], c);
                c = mfma16(a2, wz2[g][2], c);
                c = mfma16(a3, wz2[g][3], c);
                acc[m][g] = c;
            }
        }
        __syncthreads();  // (4) all waves done reading old h2

        // ---- LSTM2 gates (relu), write new h2 ----
#pragma unroll
        for (int m = 0; m < 4; ++m) {
#pragma unroll
            for (int j = 0; j < 4; ++j) {
                const float iv = sigm(acc[m][0][j] + bz2v[0]);
                const float fv = sigm(acc[m][1][j] + bz2v[1]);
                const float gv = fmaxf(acc[m][2][j] + bz2v[2], 0.0f);
                const float ov = sigm(acc[m][3][j] + bz2v[3]);
                const float cn = fv * c2[m][j] + iv * gv;
                c2[m][j] = cn;
                const float hv = ov * fmaxf(cn, 0.0f);
                Abuf[(16 * m + q * 4 + j) * STRIDE + 80 + wave * 16 + n] = f2bf(hv);
            }
        }
        // no barrier needed here: next-iteration barriers (1)/(3) precede any read of h2
    }
    __syncthreads();  // final h2 visible

    // ---- out = h2_last @ Wf + bf ----
    const int r = tid >> 2, jo = tid & 3;
    float s = bfin[jo];
    const short* hrow = &Abuf[r * STRIDE + 80];
    for (int k = 0; k < H; ++k) s += bf2f(hrow[k]) * Wf[k * D_OUT + jo];
    out[(size_t)(b0 + r) * D_OUT + jo] = s;
}

extern "C" void kernel_launch(void* const* d_in, const int* in_sizes, int n_in,
                              void* d_out, int out_size, void* d_ws, size_t ws_size,
                              hipStream_t stream) {
    const float* x  = (const float*)d_in[0];
    const float* W1 = (const float*)d_in[1];
    const float* U1 = (const float*)d_in[2];
    const float* b1 = (const float*)d_in[3];
    const float* Wd = (const float*)d_in[4];
    const float* bd = (const float*)d_in[5];
    const float* W2 = (const float*)d_in[6];
    const float* U2 = (const float*)d_in[7];
    const float* b2 = (const float*)d_in[8];
    const float* Wf = (const float*)d_in[9];
    const float* bf = (const float*)d_in[10];
    float* out = (float*)d_out;

    char* ws = (char*)d_ws;
    short* wu1 = (short*)ws;                         // 96*256*2  = 49152 B
    short* wu2 = (short*)(ws + 49152);               // 128*256*2 = 65536 B
    float* bz1 = (float*)(ws + 49152 + 65536);       // 1024 B
    float* bz2 = (float*)(ws + 49152 + 65536 + 1024);

    precompute_weights<<<1, 256, 0, stream>>>(W1, U1, b1, Wd, bd, W2, U2, b2, wu1, wu2, bz1, bz2);
    lstm_fused<<<B_TOT / BTILE, 256, 0, stream>>>(x, wu1, wu2, bz1, bz2, Wf, bf, out);
}

// Round 2
// 206.018 us; speedup vs baseline: 1.4430x; 1.4430x over previous
//
#include <hip/hip_runtime.h>

#define B_TOT 65536
#define T_STEPS 10
#define D_IN 16
#define H 64
#define G4H 256
#define D_MLP 30
#define D_OUT 4
#define BTILE 64
#define STRIDE 152  // shorts per row; 304B = 76 words -> only 2-way bank aliasing (free)

typedef short short8 __attribute__((ext_vector_type(8)));
typedef short short4_t __attribute__((ext_vector_type(4)));
typedef float float4_t __attribute__((ext_vector_type(4)));
typedef __bf16 bf16x8_t __attribute__((ext_vector_type(8)));

static __device__ __forceinline__ short f2bf(float f) {
    unsigned u = __builtin_bit_cast(unsigned, f);
    unsigned r = (u + 0x7FFFu + ((u >> 16) & 1u)) >> 16;
    return (short)(unsigned short)r;
}
static __device__ __forceinline__ float bf2f(short s) {
    unsigned u = ((unsigned)(unsigned short)s) << 16;
    return __builtin_bit_cast(float, u);
}
static __device__ __forceinline__ float4_t mfma16(short8 a, short8 b, float4_t c) {
    return __builtin_amdgcn_mfma_f32_16x16x32_bf16(
        __builtin_bit_cast(bf16x8_t, a), __builtin_bit_cast(bf16x8_t, b), c, 0, 0, 0);
}
static __device__ __forceinline__ float sigm(float x) {
    return __builtin_amdgcn_rcpf(1.0f + __expf(-x));
}
static __device__ __forceinline__ float tanh_f(float x) {
    return 1.0f - 2.0f * __builtin_amdgcn_rcpf(1.0f + __expf(2.0f * x));
}

// wu1 = [W1(16); U1(64); zeros(16)] (96x256), wu2 = [Wd@W2(64); U2(64)] (128x256),
// bz1 = b1, bz2 = bd@W2 + b2.  One (row, all-cols) slab per block.
__global__ void precompute_weights(const float* __restrict__ W1, const float* __restrict__ U1,
                                   const float* __restrict__ b1, const float* __restrict__ Wd,
                                   const float* __restrict__ bd, const float* __restrict__ W2,
                                   const float* __restrict__ U2, const float* __restrict__ b2,
                                   short* __restrict__ wu1, short* __restrict__ wu2,
                                   float* __restrict__ bz1, float* __restrict__ bz2) {
    const int j = threadIdx.x;   // 0..255 column
    const int r = blockIdx.x;    // 0..224
    if (r < 96) {
        float v = 0.0f;
        if (r < 16)      v = W1[r * G4H + j];
        else if (r < 80) v = U1[(r - 16) * G4H + j];
        wu1[r * G4H + j] = f2bf(v);
    } else if (r < 160) {
        const int rr = r - 96;
        float s = 0.0f;
        for (int k = 0; k < D_MLP; ++k) s += Wd[rr * D_MLP + k] * W2[k * G4H + j];
        wu2[rr * G4H + j] = f2bf(s);
    } else if (r < 224) {
        const int rr = r - 160;
        wu2[(64 + rr) * G4H + j] = f2bf(U2[rr * G4H + j]);
    } else {
        bz1[j] = b1[j];
        float s = b2[j];
        for (int k = 0; k < D_MLP; ++k) s += bd[k] * W2[k * G4H + j];
        bz2[j] = s;
    }
}

__global__ __launch_bounds__(256)
__attribute__((amdgpu_waves_per_eu(2, 2)))
void lstm_fused(
    const float* __restrict__ x, const short* __restrict__ wu1, const short* __restrict__ wu2,
    const float* __restrict__ bz1, const float* __restrict__ bz2,
    const float* __restrict__ Wf, const float* __restrict__ bfin, float* __restrict__ out) {
    // double-buffered activation plane: cols [0,16)=x_t  [16,80)=h1  [80,144)=h2
    __shared__ __align__(16) short Abuf[2][BTILE * STRIDE];

    const int tid  = threadIdx.x;
    const int lane = tid & 63;
    const int wave = tid >> 6;         // 0..3
    const int q    = lane >> 4;        // k-quad
    const int n    = lane & 15;        // col-in-tile / batch-row-in-A
    const int b0   = blockIdx.x * BTILE;

    // ---- persistent weight B-fragments (registers) ----
    // wave w owns gate-col slice [g*64 + w*16, +16) for g = i,f,g,o
    short8 wz1[4][3];
    short8 wz2[4][4];
    float bz1v[4], bz2v[4];
#pragma unroll
    for (int g = 0; g < 4; ++g) {
        const int col = g * 64 + wave * 16 + n;
#pragma unroll
        for (int k = 0; k < 3; ++k) {
#pragma unroll
            for (int j = 0; j < 8; ++j)
                wz1[g][k][j] = wu1[(k * 32 + q * 8 + j) * G4H + col];
        }
#pragma unroll
        for (int k = 0; k < 4; ++k) {
#pragma unroll
            for (int j = 0; j < 8; ++j)
                wz2[g][k][j] = wu2[(k * 32 + q * 8 + j) * G4H + col];
        }
        bz1v[g] = bz1[col];
        bz2v[g] = bz2[col];
    }

    // zero buffer 0 (h1/h2 must start at 0; x cols overwritten below)
    for (int i = tid; i < BTILE * STRIDE; i += 256) Abuf[0][i] = 0;

    float4_t c1[4], c2[4];
#pragma unroll
    for (int m = 0; m < 4; ++m) { c1[m] = (float4_t){0,0,0,0}; c2[m] = (float4_t){0,0,0,0}; }

    const int xr = tid >> 2, xs = tid & 3;  // x staging: row 0..63, 4-float segment
    const float* xbase = x + (size_t)(b0 + xr) * (T_STEPS * D_IN) + xs * 4;

    float4 xv = *(const float4*)xbase;      // x_0
    __syncthreads();                        // zeros done
    {
        short4_t s4;
        s4[0] = f2bf(xv.x); s4[1] = f2bf(xv.y); s4[2] = f2bf(xv.z); s4[3] = f2bf(xv.w);
        *(short4_t*)&Abuf[0][xr * STRIDE + xs * 4] = s4;
    }
    __syncthreads();                        // x_0 staged

    for (int t = 0; t < T_STEPS; ++t) {
        const int cur = t & 1;
        const short* cb = Abuf[cur];
        short* nb = Abuf[cur ^ 1];

        // prefetch x_{t+1} (clamped) — consumed at end of phase 2
        const int tn = (t + 1 < T_STEPS) ? t + 1 : T_STEPS - 1;
        xv = *(const float4*)(xbase + tn * D_IN);

        // ---- phase 1: z1 = [x_t | h1_old | pad] @ WU1, gates fused per m, h1_new -> nb ----
#pragma unroll
        for (int m = 0; m < 4; ++m) {
            const int arow = (16 * m + n) * STRIDE + q * 8;
            const short8 a0 = *(const short8*)&cb[arow + 0];
            const short8 a1 = *(const short8*)&cb[arow + 32];
            const short8 a2 = *(const short8*)&cb[arow + 64];  // rows 80..96 of WU1 are zero
            float4_t ac[4];
#pragma unroll
            for (int g = 0; g < 4; ++g) {
                float4_t c = (float4_t){bz1v[g], bz1v[g], bz1v[g], bz1v[g]};
                c = mfma16(a0, wz1[g][0], c);
                c = mfma16(a1, wz1[g][1], c);
                c = mfma16(a2, wz1[g][2], c);
                ac[g] = c;
            }
#pragma unroll
            for (int j = 0; j < 4; ++j) {
                const float iv = sigm(ac[0][j]);
                const float fv = sigm(ac[1][j]);
                const float gv = tanh_f(ac[2][j]);
                const float ov = sigm(ac[3][j]);
                const float cn = fv * c1[m][j] + iv * gv;
                c1[m][j] = cn;
                const float hv = ov * tanh_f(cn);
                // C/D layout: row = 16m + q*4 + j, col = wave*16 + n
                nb[(16 * m + q * 4 + j) * STRIDE + 16 + wave * 16 + n] = f2bf(hv);
            }
        }
        __syncthreads();  // (1) h1_new visible

        // ---- phase 2: z2 = [h1_new | h2_old] @ [Wc; U2], gates fused per m, h2_new -> nb ----
#pragma unroll
        for (int m = 0; m < 4; ++m) {
            const int arow = (16 * m + n) * STRIDE + q * 8;
            const short8 a0 = *(const short8*)&nb[arow + 16];
            const short8 a1 = *(const short8*)&nb[arow + 48];
            const short8 a2 = *(const short8*)&cb[arow + 80];
            const short8 a3 = *(const short8*)&cb[arow + 112];
            float4_t ac[4];
#pragma unroll
            for (int g = 0; g < 4; ++g) {
                float4_t c = (float4_t){bz2v[g], bz2v[g], bz2v[g], bz2v[g]};
                c = mfma16(a0, wz2[g][0], c);
                c = mfma16(a1, wz2[g][1], c);
                c = mfma16(a2, wz2[g][2], c);
                c = mfma16(a3, wz2[g][3], c);
                ac[g] = c;
            }
#pragma unroll
            for (int j = 0; j < 4; ++j) {
                const float iv = sigm(ac[0][j]);
                const float fv = sigm(ac[1][j]);
                const float gv = fmaxf(ac[2][j], 0.0f);
                const float ov = sigm(ac[3][j]);
                const float cn = fv * c2[m][j] + iv * gv;
                c2[m][j] = cn;
                const float hv = ov * fmaxf(cn, 0.0f);
                nb[(16 * m + q * 4 + j) * STRIDE + 80 + wave * 16 + n] = f2bf(hv);
            }
        }
        // stage prefetched x_{t+1} into nb.x (no reader until next t)
        {
            short4_t s4;
            s4[0] = f2bf(xv.x); s4[1] = f2bf(xv.y); s4[2] = f2bf(xv.z); s4[3] = f2bf(xv.w);
            *(short4_t*)&nb[xr * STRIDE + xs * 4] = s4;
        }
        __syncthreads();  // (2) h2_new + x_{t+1} visible; nb becomes cb
    }

    // ---- out = h2_last @ Wf + bf ;  final h2 lives in Abuf[T_STEPS & 1] ----
    const int r = tid >> 2, jo = tid & 3;
    float s = bfin[jo];
    const short* hrow = &Abuf[T_STEPS & 1][r * STRIDE + 80];
#pragma unroll 8
    for (int k = 0; k < H; ++k) s += bf2f(hrow[k]) * Wf[k * D_OUT + jo];
    out[(size_t)(b0 + r) * D_OUT + jo] = s;
}

extern "C" void kernel_launch(void* const* d_in, const int* in_sizes, int n_in,
                              void* d_out, int out_size, void* d_ws, size_t ws_size,
                              hipStream_t stream) {
    const float* x  = (const float*)d_in[0];
    const float* W1 = (const float*)d_in[1];
    const float* U1 = (const float*)d_in[2];
    const float* b1 = (const float*)d_in[3];
    const float* Wd = (const float*)d_in[4];
    const float* bd = (const float*)d_in[5];
    const float* W2 = (const float*)d_in[6];
    const float* U2 = (const float*)d_in[7];
    const float* b2 = (const float*)d_in[8];
    const float* Wf = (const float*)d_in[9];
    const float* bf = (const float*)d_in[10];
    float* out = (float*)d_out;

    char* ws = (char*)d_ws;
    short* wu1 = (short*)ws;                         // 96*256*2  = 49152 B
    short* wu2 = (short*)(ws + 49152);               // 128*256*2 = 65536 B
    float* bz1 = (float*)(ws + 49152 + 65536);       // 1024 B
    float* bz2 = (float*)(ws + 49152 + 65536 + 1024);

    precompute_weights<<<225, 256, 0, stream>>>(W1, U1, b1, Wd, bd, W2, U2, b2, wu1, wu2, bz1, bz2);
    lstm_fused<<<B_TOT / BTILE, 256, 0, stream>>>(x, wu1, wu2, bz1, bz2, Wf, bf, out);
}

// Round 3
// 205.055 us; speedup vs baseline: 1.4497x; 1.0047x over previous
//
#include <hip/hip_runtime.h>

#define B_TOT 65536
#define T_STEPS 10
#define D_IN 16
#define H 64
#define G4H 256
#define D_MLP 30
#define D_OUT 4
#define BTILE 64
#define S1 88    // K1 LDS stride (shorts): cols x(16)|h1(64); 44 dw -> 2-way only (free)
#define S2 136   // K2 LDS stride: cols h1(64)|h2(64); 68 dw -> 2-way only (free)
#define SF 152   // fused-fallback stride

typedef short short8 __attribute__((ext_vector_type(8)));
typedef short short4_t __attribute__((ext_vector_type(4)));
typedef float float4_t __attribute__((ext_vector_type(4)));
typedef __bf16 bf16x8_t __attribute__((ext_vector_type(8)));

// cheap bf16 round (round-half-up, 2 ops): fine vs 5.9e-3 threshold
static __device__ __forceinline__ short f2bf(float f) {
    unsigned u = __builtin_bit_cast(unsigned, f);
    return (short)(unsigned short)((u + 0x8000u) >> 16);
}
static __device__ __forceinline__ short f2bf_rne(float f) {  // weights (precompute only)
    unsigned u = __builtin_bit_cast(unsigned, f);
    unsigned r = (u + 0x7FFFu + ((u >> 16) & 1u)) >> 16;
    return (short)(unsigned short)r;
}
static __device__ __forceinline__ float bf2f(short s) {
    unsigned u = ((unsigned)(unsigned short)s) << 16;
    return __builtin_bit_cast(float, u);
}
static __device__ __forceinline__ float4_t mfma16(short8 a, short8 b, float4_t c) {
    return __builtin_amdgcn_mfma_f32_16x16x32_bf16(
        __builtin_bit_cast(bf16x8_t, a), __builtin_bit_cast(bf16x8_t, b), c, 0, 0, 0);
}
static __device__ __forceinline__ float sigm(float x) {
    return __builtin_amdgcn_rcpf(1.0f + __expf(-x));
}
static __device__ __forceinline__ float tanh_f(float x) {
    return 1.0f - 2.0f * __builtin_amdgcn_rcpf(1.0f + __expf(2.0f * x));
}

// wu1 (96x256, bf16), K-tile layout for A=[x(0:16)|h1(16:80)], tiles at A-cols 0/32/48:
//   k=0 rows: [W1(16); U1[0:16]]   (A cols 0..32)
//   k=1 rows: U1[16:48]            (A cols 32..64)
//   k=2 rows: [zeros(16); U1[48:64]] (A cols 48..80 -- overlap trick)
// wu2 (128x256): [Wd@W2(64); U2(64)].  bz1 = b1, bz2 = bd@W2 + b2.
__global__ void precompute_weights(const float* __restrict__ W1, const float* __restrict__ U1,
                                   const float* __restrict__ b1, const float* __restrict__ Wd,
                                   const float* __restrict__ bd, const float* __restrict__ W2,
                                   const float* __restrict__ U2, const float* __restrict__ b2,
                                   short* __restrict__ wu1, short* __restrict__ wu2,
                                   float* __restrict__ bz1, float* __restrict__ bz2) {
    const int j = threadIdx.x;   // 0..255 column
    const int r = blockIdx.x;    // 0..224
    if (r < 96) {
        const int k = r >> 5, rr = r & 31;
        float v = 0.0f;
        if (k == 0)      v = (rr < 16) ? W1[rr * G4H + j] : U1[(rr - 16) * G4H + j];
        else if (k == 1) v = U1[(16 + rr) * G4H + j];
        else             v = (rr < 16) ? 0.0f : U1[(32 + rr) * G4H + j];
        wu1[r * G4H + j] = f2bf_rne(v);
    } else if (r < 160) {
        const int rr = r - 96;
        float s = 0.0f;
        for (int k = 0; k < D_MLP; ++k) s += Wd[rr * D_MLP + k] * W2[k * G4H + j];
        wu2[rr * G4H + j] = f2bf_rne(s);
    } else if (r < 224) {
        const int rr = r - 160;
        wu2[(64 + rr) * G4H + j] = f2bf_rne(U2[rr * G4H + j]);
    } else {
        bz1[j] = b1[j];
        float s = b2[j];
        for (int k = 0; k < D_MLP; ++k) s += bd[k] * W2[k * G4H + j];
        bz2[j] = s;
    }
}

// ---------------- K1: LSTM layer 1, writes h1[t][b][64] bf16 to global ----------------
__global__ __launch_bounds__(256)
__attribute__((amdgpu_waves_per_eu(3, 4)))
void lstm1(const float* __restrict__ x, const short* __restrict__ wu1,
           const float* __restrict__ bz1, short* __restrict__ h1g) {
    __shared__ __align__(16) short A[2][BTILE * S1];  // cols [0,16)=x_t  [16,80)=h1

    const int tid  = threadIdx.x;
    const int lane = tid & 63;
    const int wave = tid >> 6;
    const int q    = lane >> 4;
    const int n    = lane & 15;
    const int b0   = blockIdx.x * BTILE;

    short8 wz[4][3];
    float bzv[4];
#pragma unroll
    for (int g = 0; g < 4; ++g) {
        const int col = g * 64 + wave * 16 + n;
#pragma unroll
        for (int k = 0; k < 3; ++k)
#pragma unroll
            for (int j = 0; j < 8; ++j)
                wz[g][k][j] = wu1[(k * 32 + q * 8 + j) * G4H + col];
        bzv[g] = bz1[col];
    }

    for (int i = tid; i < BTILE * S1; i += 256) A[0][i] = 0;

    float4_t c1[4];
#pragma unroll
    for (int m = 0; m < 4; ++m) c1[m] = (float4_t){0, 0, 0, 0};

    const int xr = tid >> 2, xs = tid & 3;
    const float* xbase = x + (size_t)(b0 + xr) * (T_STEPS * D_IN) + xs * 4;
    float4 xv = *(const float4*)xbase;
    __syncthreads();
    {
        short4_t s4;
        s4[0] = f2bf(xv.x); s4[1] = f2bf(xv.y); s4[2] = f2bf(xv.z); s4[3] = f2bf(xv.w);
        *(short4_t*)&A[0][xr * S1 + xs * 4] = s4;
    }
    __syncthreads();

    for (int t = 0; t < T_STEPS; ++t) {
        const short* cb = A[t & 1];
        short* nb = A[(t & 1) ^ 1];
        const int tn = (t + 1 < T_STEPS) ? t + 1 : T_STEPS - 1;
        xv = *(const float4*)(xbase + tn * D_IN);

#pragma unroll
        for (int m = 0; m < 4; ++m) {
            const int arow = (16 * m + n) * S1 + q * 8;
            const short8 a0 = *(const short8*)&cb[arow + 0];
            const short8 a1 = *(const short8*)&cb[arow + 32];
            const short8 a2 = *(const short8*)&cb[arow + 48];
            float4_t ac[4];
#pragma unroll
            for (int g = 0; g < 4; ++g) {
                float4_t c = (float4_t){bzv[g], bzv[g], bzv[g], bzv[g]};
                c = mfma16(a0, wz[g][0], c);
                c = mfma16(a1, wz[g][1], c);
                c = mfma16(a2, wz[g][2], c);
                ac[g] = c;
            }
#pragma unroll
            for (int j = 0; j < 4; ++j) {
                const float iv = sigm(ac[0][j]);
                const float fv = sigm(ac[1][j]);
                const float gv = tanh_f(ac[2][j]);
                const float ov = sigm(ac[3][j]);
                const float cn = fv * c1[m][j] + iv * gv;
                c1[m][j] = cn;
                const short hb = f2bf(ov * tanh_f(cn));
                const int row = 16 * m + q * 4 + j;
                nb[row * S1 + 16 + wave * 16 + n] = hb;
                h1g[((size_t)t * B_TOT + b0 + row) * H + wave * 16 + n] = hb;
            }
        }
        {
            short4_t s4;
            s4[0] = f2bf(xv.x); s4[1] = f2bf(xv.y); s4[2] = f2bf(xv.z); s4[3] = f2bf(xv.w);
            *(short4_t*)&nb[xr * S1 + xs * 4] = s4;
        }
        __syncthreads();
    }
}

// ---------------- K2: LSTM layer 2 (relu), reads h1g, writes final projection ----------------
__global__ __launch_bounds__(256)
__attribute__((amdgpu_waves_per_eu(3, 4)))
void lstm2(const short* __restrict__ h1g, const short* __restrict__ wu2,
           const float* __restrict__ bz2, const float* __restrict__ Wf,
           const float* __restrict__ bfin, float* __restrict__ out) {
    __shared__ __align__(16) short A[2][BTILE * S2];  // cols [0,64)=h1_t  [64,128)=h2

    const int tid  = threadIdx.x;
    const int lane = tid & 63;
    const int wave = tid >> 6;
    const int q    = lane >> 4;
    const int n    = lane & 15;
    const int b0   = blockIdx.x * BTILE;

    short8 wz[4][4];
    float bzv[4];
#pragma unroll
    for (int g = 0; g < 4; ++g) {
        const int col = g * 64 + wave * 16 + n;
#pragma unroll
        for (int k = 0; k < 4; ++k)
#pragma unroll
            for (int j = 0; j < 8; ++j)
                wz[g][k][j] = wu2[(k * 32 + q * 8 + j) * G4H + col];
        bzv[g] = bz2[col];
    }

    for (int i = tid; i < BTILE * S2; i += 256) A[0][i] = 0;

    float4_t c2[4];
#pragma unroll
    for (int m = 0; m < 4; ++m) c2[m] = (float4_t){0, 0, 0, 0};

    // h1 staging: 64 rows x 64 cols bf16 = 128B/row; 4 threads/row x 32B
    const int hr = tid >> 2, hs = tid & 3;
    const short* hbase = h1g + (size_t)(b0 + hr) * H + hs * 16;
    __syncthreads();  // zeros done
    {
        const short8 p0 = *(const short8*)(hbase + 0);
        const short8 p1 = *(const short8*)(hbase + 8);
        *(short8*)&A[0][hr * S2 + hs * 16 + 0] = p0;
        *(short8*)&A[0][hr * S2 + hs * 16 + 8] = p1;
    }
    __syncthreads();

    for (int t = 0; t < T_STEPS; ++t) {
        const short* cb = A[t & 1];
        short* nb = A[(t & 1) ^ 1];
        const int tn = (t + 1 < T_STEPS) ? t + 1 : T_STEPS - 1;
        const short* hpb = hbase + (size_t)tn * B_TOT * H;
        const short8 p0 = *(const short8*)(hpb + 0);
        const short8 p1 = *(const short8*)(hpb + 8);

#pragma unroll
        for (int m = 0; m < 4; ++m) {
            const int arow = (16 * m + n) * S2 + q * 8;
            const short8 a0 = *(const short8*)&cb[arow + 0];
            const short8 a1 = *(const short8*)&cb[arow + 32];
            const short8 a2 = *(const short8*)&cb[arow + 64];
            const short8 a3 = *(const short8*)&cb[arow + 96];
            float4_t ac[4];
#pragma unroll
            for (int g = 0; g < 4; ++g) {
                float4_t c = (float4_t){bzv[g], bzv[g], bzv[g], bzv[g]};
                c = mfma16(a0, wz[g][0], c);
                c = mfma16(a1, wz[g][1], c);
                c = mfma16(a2, wz[g][2], c);
                c = mfma16(a3, wz[g][3], c);
                ac[g] = c;
            }
#pragma unroll
            for (int j = 0; j < 4; ++j) {
                const float iv = sigm(ac[0][j]);
                const float fv = sigm(ac[1][j]);
                const float gv = fmaxf(ac[2][j], 0.0f);
                const float ov = sigm(ac[3][j]);
                const float cn = fv * c2[m][j] + iv * gv;
                c2[m][j] = cn;
                const float hv = ov * fmaxf(cn, 0.0f);
                nb[(16 * m + q * 4 + j) * S2 + 64 + wave * 16 + n] = f2bf(hv);
            }
        }
        *(short8*)&nb[hr * S2 + hs * 16 + 0] = p0;
        *(short8*)&nb[hr * S2 + hs * 16 + 8] = p1;
        __syncthreads();
    }

    // out = h2_last @ Wf + bf ; final h2 in A[T_STEPS & 1]
    const int r = tid >> 2, jo = tid & 3;
    float s = bfin[jo];
    const short* hrow = &A[T_STEPS & 1][r * S2 + 64];
#pragma unroll 8
    for (int k = 0; k < H; ++k) s += bf2f(hrow[k]) * Wf[k * D_OUT + jo];
    out[(size_t)(b0 + r) * D_OUT + jo] = s;
}

// ---------------- fallback: fused single kernel (R2 structure, trimmed) ----------------
__global__ __launch_bounds__(256)
__attribute__((amdgpu_waves_per_eu(2, 2)))
void lstm_fused(
    const float* __restrict__ x, const short* __restrict__ wu1, const short* __restrict__ wu2,
    const float* __restrict__ bz1, const float* __restrict__ bz2,
    const float* __restrict__ Wf, const float* __restrict__ bfin, float* __restrict__ out) {
    __shared__ __align__(16) short Abuf[2][BTILE * SF];  // [0,16)=x [16,80)=h1 [80,144)=h2

    const int tid  = threadIdx.x;
    const int lane = tid & 63;
    const int wave = tid >> 6;
    const int q    = lane >> 4;
    const int n    = lane & 15;
    const int b0   = blockIdx.x * BTILE;

    short8 wz1[4][3];
    short8 wz2[4][4];
    float bz1v[4], bz2v[4];
#pragma unroll
    for (int g = 0; g < 4; ++g) {
        const int col = g * 64 + wave * 16 + n;
#pragma unroll
        for (int k = 0; k < 3; ++k)
#pragma unroll
            for (int j = 0; j < 8; ++j)
                wz1[g][k][j] = wu1[(k * 32 + q * 8 + j) * G4H + col];
#pragma unroll
        for (int k = 0; k < 4; ++k)
#pragma unroll
            for (int j = 0; j < 8; ++j)
                wz2[g][k][j] = wu2[(k * 32 + q * 8 + j) * G4H + col];
        bz1v[g] = bz1[col];
        bz2v[g] = bz2[col];
    }

    for (int i = tid; i < BTILE * SF; i += 256) Abuf[0][i] = 0;

    float4_t c1[4], c2[4];
#pragma unroll
    for (int m = 0; m < 4; ++m) { c1[m] = (float4_t){0,0,0,0}; c2[m] = (float4_t){0,0,0,0}; }

    const int xr = tid >> 2, xs = tid & 3;
    const float* xbase = x + (size_t)(b0 + xr) * (T_STEPS * D_IN) + xs * 4;
    float4 xv = *(const float4*)xbase;
    __syncthreads();
    {
        short4_t s4;
        s4[0] = f2bf(xv.x); s4[1] = f2bf(xv.y); s4[2] = f2bf(xv.z); s4[3] = f2bf(xv.w);
        *(short4_t*)&Abuf[0][xr * SF + xs * 4] = s4;
    }
    __syncthreads();

    for (int t = 0; t < T_STEPS; ++t) {
        const int cur = t & 1;
        const short* cb = Abuf[cur];
        short* nb = Abuf[cur ^ 1];
        const int tn = (t + 1 < T_STEPS) ? t + 1 : T_STEPS - 1;
        xv = *(const float4*)(xbase + tn * D_IN);

#pragma unroll
        for (int m = 0; m < 4; ++m) {
            const int arow = (16 * m + n) * SF + q * 8;
            const short8 a0 = *(const short8*)&cb[arow + 0];
            const short8 a1 = *(const short8*)&cb[arow + 32];
            const short8 a2 = *(const short8*)&cb[arow + 48];  // overlap-tile layout
            float4_t ac[4];
#pragma unroll
            for (int g = 0; g < 4; ++g) {
                float4_t c = (float4_t){bz1v[g], bz1v[g], bz1v[g], bz1v[g]};
                c = mfma16(a0, wz1[g][0], c);
                c = mfma16(a1, wz1[g][1], c);
                c = mfma16(a2, wz1[g][2], c);
                ac[g] = c;
            }
#pragma unroll
            for (int j = 0; j < 4; ++j) {
                const float iv = sigm(ac[0][j]);
                const float fv = sigm(ac[1][j]);
                const float gv = tanh_f(ac[2][j]);
                const float ov = sigm(ac[3][j]);
                const float cn = fv * c1[m][j] + iv * gv;
                c1[m][j] = cn;
                nb[(16 * m + q * 4 + j) * SF + 16 + wave * 16 + n] = f2bf(ov * tanh_f(cn));
            }
        }
        __syncthreads();

#pragma unroll
        for (int m = 0; m < 4; ++m) {
            const int arow = (16 * m + n) * SF + q * 8;
            const short8 a0 = *(const short8*)&nb[arow + 16];
            const short8 a1 = *(const short8*)&nb[arow + 48];
            const short8 a2 = *(const short8*)&cb[arow + 80];
            const short8 a3 = *(const short8*)&cb[arow + 112];
            float4_t ac[4];
#pragma unroll
            for (int g = 0; g < 4; ++g) {
                float4_t c = (float4_t){bz2v[g], bz2v[g], bz2v[g], bz2v[g]};
                c = mfma16(a0, wz2[g][0], c);
                c = mfma16(a1, wz2[g][1], c);
                c = mfma16(a2, wz2[g][2], c);
                c = mfma16(a3, wz2[g][3], c);
                ac[g] = c;
            }
#pragma unroll
            for (int j = 0; j < 4; ++j) {
                const float iv = sigm(ac[0][j]);
                const float fv = sigm(ac[1][j]);
                const float gv = fmaxf(ac[2][j], 0.0f);
                const float ov = sigm(ac[3][j]);
                const float cn = fv * c2[m][j] + iv * gv;
                c2[m][j] = cn;
                nb[(16 * m + q * 4 + j) * SF + 80 + wave * 16 + n] = f2bf(ov * fmaxf(cn, 0.0f));
            }
        }
        {
            short4_t s4;
            s4[0] = f2bf(xv.x); s4[1] = f2bf(xv.y); s4[2] = f2bf(xv.z); s4[3] = f2bf(xv.w);
            *(short4_t*)&nb[xr * SF + xs * 4] = s4;
        }
        __syncthreads();
    }

    const int r = tid >> 2, jo = tid & 3;
    float s = bfin[jo];
    const short* hrow = &Abuf[T_STEPS & 1][r * SF + 80];
#pragma unroll 8
    for (int k = 0; k < H; ++k) s += bf2f(hrow[k]) * Wf[k * D_OUT + jo];
    out[(size_t)(b0 + r) * D_OUT + jo] = s;
}

extern "C" void kernel_launch(void* const* d_in, const int* in_sizes, int n_in,
                              void* d_out, int out_size, void* d_ws, size_t ws_size,
                              hipStream_t stream) {
    const float* x  = (const float*)d_in[0];
    const float* W1 = (const float*)d_in[1];
    const float* U1 = (const float*)d_in[2];
    const float* b1 = (const float*)d_in[3];
    const float* Wd = (const float*)d_in[4];
    const float* bd = (const float*)d_in[5];
    const float* W2 = (const float*)d_in[6];
    const float* U2 = (const float*)d_in[7];
    const float* b2 = (const float*)d_in[8];
    const float* Wf = (const float*)d_in[9];
    const float* bf = (const float*)d_in[10];
    float* out = (float*)d_out;

    char* ws = (char*)d_ws;
    short* wu1 = (short*)ws;                         // 49152 B
    short* wu2 = (short*)(ws + 49152);               // 65536 B
    float* bz1 = (float*)(ws + 49152 + 65536);       // 1024 B
    float* bz2 = (float*)(ws + 49152 + 65536 + 1024);
    short* h1g = (short*)(ws + 116736);              // 10*65536*64*2 = 83886080 B

    precompute_weights<<<225, 256, 0, stream>>>(W1, U1, b1, Wd, bd, W2, U2, b2, wu1, wu2, bz1, bz2);

    const size_t need = 116736ull + (size_t)T_STEPS * B_TOT * H * 2;
    if (ws_size >= need) {
        lstm1<<<B_TOT / BTILE, 256, 0, stream>>>(x, wu1, bz1, h1g);
        lstm2<<<B_TOT / BTILE, 256, 0, stream>>>(h1g, wu2, bz2, Wf, bf, out);
    } else {
        lstm_fused<<<B_TOT / BTILE, 256, 0, stream>>>(x, wu1, wu2, bz1, bz2, Wf, bf, out);
    }
}